// Round 4
// baseline (742.146 us; speedup 1.0000x reference)
//
#include <hip/hip_runtime.h>
#include <math.h>

constexpr int NUM_CLASSES = 100;
constexpr int CACHE_SIZE  = 50;
constexpr int NPROT       = 5000;   // NUM_CLASSES*CACHE_SIZE
constexpr int FD          = 128;
constexpr int BATCH       = 2048;
constexpr int NROWS       = 4096;   // BATCH*NVIEWS
constexpr int TOPK        = 10;
constexpr float INV_EPS   = 20.0f;  // 1/0.05
constexpr float INV_TEMP  = 10.0f;  // 1/0.1
constexpr float PROTO_M   = 0.99f;
constexpr int NSPLIT      = 64;     // colsum row-splits (320 blocks)
constexpr int PLD         = 5120;   // padded leading dim for partial buffers

typedef __attribute__((ext_vector_type(8))) short bf16x8;
typedef __attribute__((ext_vector_type(4))) float f32x4;
typedef __attribute__((ext_vector_type(4))) _Float16 f16x4;
typedef __attribute__((ext_vector_type(8))) _Float16 f16x8;

// ---------- helpers ----------
__device__ __forceinline__ float blockReduceSum(float v) {
  __shared__ float tmp[8];
  const int lane = threadIdx.x & 63;
  const int wid  = threadIdx.x >> 6;
  #pragma unroll
  for (int o = 32; o > 0; o >>= 1) v += __shfl_down(v, o, 64);
  __syncthreads();               // protect tmp across repeated calls
  if (lane == 0) tmp[wid] = v;
  __syncthreads();
  const int nw = (blockDim.x + 63) >> 6;
  float s = 0.f;
  for (int i = 0; i < nw; ++i) s += tmp[i];
  return s;                      // broadcast to all threads
}

__device__ __forceinline__ short f2bf(float x) {   // RNE fp32 -> bf16 bits
  union { float f; unsigned u; } v; v.f = x;
  const unsigned r = v.u + 0x7fffu + ((v.u >> 16) & 1u);
  return (short)(r >> 16);
}
__device__ __forceinline__ float bf2f(short h) {
  union { float f; unsigned u; } v; v.u = ((unsigned)(unsigned short)h) << 16;
  return v.f;
}

// ---------- build feats (+ bf16 hi/lo split): feats[v*B+b] = features[b,v,:] ----------
__global__ void k_build_feats(const float* __restrict__ features,
                              float* __restrict__ feats,
                              short* __restrict__ fhi, short* __restrict__ flo) {
  const int t = blockIdx.x * blockDim.x + threadIdx.x;   // one float4 each
  if (t >= NROWS * (FD / 4)) return;
  const int n  = t >> 5;            // / (128/4)
  const int d4 = (t & 31) << 2;
  const int b  = n & (BATCH - 1);
  const int v  = n >> 11;
  const float4 src = *reinterpret_cast<const float4*>(features + ((size_t)b * 2 + v) * FD + d4);
  *reinterpret_cast<float4*>(feats + (size_t)n * FD + d4) = src;
  short4 h, l;
  h.x = f2bf(src.x); l.x = f2bf(src.x - bf2f(h.x));
  h.y = f2bf(src.y); l.y = f2bf(src.y - bf2f(h.y));
  h.z = f2bf(src.z); l.z = f2bf(src.z - bf2f(h.z));
  h.w = f2bf(src.w); l.w = f2bf(src.w - bf2f(h.w));
  *reinterpret_cast<short4*>(fhi + (size_t)n * FD + d4) = h;
  *reinterpret_cast<short4*>(flo + (size_t)n * FD + d4) = l;
}

// ---------- split any fp32 [n][128] matrix into bf16 hi/lo ----------
__global__ void k_split(const float* __restrict__ src, int nelem4,
                        short* __restrict__ hi, short* __restrict__ lo) {
  const int t = blockIdx.x * blockDim.x + threadIdx.x;
  if (t >= nelem4) return;
  const float4 v = *reinterpret_cast<const float4*>(src + (size_t)t * 4);
  short4 h, l;
  h.x = f2bf(v.x); l.x = f2bf(v.x - bf2f(h.x));
  h.y = f2bf(v.y); l.y = f2bf(v.y - bf2f(h.y));
  h.z = f2bf(v.z); l.z = f2bf(v.z - bf2f(h.z));
  h.w = f2bf(v.w); l.w = f2bf(v.w - bf2f(h.w));
  *reinterpret_cast<short4*>(hi + (size_t)t * 4) = h;
  *reinterpret_cast<short4*>(lo + (size_t)t * 4) = l;
}

// ---------- MFMA GEMM: C[m][n] = sum_d A[m][d]*B[n][d], split-bf16 3-product ----------
// Output C stored f16. Fused epilogue: colpart[slot][n] = sum_m exp(C_f16*20)
// per (block-row, wave) slot (slot = blockIdx.y*4 + wid, 128 slots total).
__global__ __launch_bounds__(256) void k_gemm_mfma(
    const short* __restrict__ Ahi, const short* __restrict__ Alo,
    const short* __restrict__ Bhi, const short* __restrict__ Blo,
    int Nb, _Float16* __restrict__ C, float* __restrict__ colpart) {
  const int tid  = threadIdx.x;
  const int wid  = tid >> 6;
  const int lane = tid & 63;
  const int lr   = lane & 15;      // fragment row/col
  const int kg   = lane >> 4;      // k-group (0..3)
  const int m0   = blockIdx.y * 128 + wid * 32;
  const int n0   = blockIdx.x * 128;

  f32x4 acc[2][8];
  #pragma unroll
  for (int i = 0; i < 2; ++i)
    #pragma unroll
    for (int j = 0; j < 8; ++j) acc[i][j] = (f32x4){0.f, 0.f, 0.f, 0.f};

  int colc[8]; bool cval[8];
  #pragma unroll
  for (int j = 0; j < 8; ++j) {
    const int col = n0 + j * 16 + lr;
    cval[j] = (col < Nb);
    colc[j] = cval[j] ? col : (Nb - 1);
  }
  const bf16x8 bz = {0, 0, 0, 0, 0, 0, 0, 0};

  #pragma unroll
  for (int kk = 0; kk < 4; ++kk) {
    const int kb = kk * 32 + kg * 8;
    bf16x8 ah[2], al[2], bh[8], bl[8];
    #pragma unroll
    for (int i = 0; i < 2; ++i) {
      const size_t off = (size_t)(m0 + i * 16 + lr) * FD + kb;
      ah[i] = *reinterpret_cast<const bf16x8*>(Ahi + off);
      al[i] = *reinterpret_cast<const bf16x8*>(Alo + off);
    }
    #pragma unroll
    for (int j = 0; j < 8; ++j) {
      const size_t off = (size_t)colc[j] * FD + kb;
      bh[j] = cval[j] ? *reinterpret_cast<const bf16x8*>(Bhi + off) : bz;
      bl[j] = cval[j] ? *reinterpret_cast<const bf16x8*>(Blo + off) : bz;
    }
    #pragma unroll
    for (int i = 0; i < 2; ++i)
      #pragma unroll
      for (int j = 0; j < 8; ++j) {
        acc[i][j] = __builtin_amdgcn_mfma_f32_16x16x32_bf16(ah[i], bh[j], acc[i][j], 0, 0, 0);
        acc[i][j] = __builtin_amdgcn_mfma_f32_16x16x32_bf16(ah[i], bl[j], acc[i][j], 0, 0, 0);
        acc[i][j] = __builtin_amdgcn_mfma_f32_16x16x32_bf16(al[i], bh[j], acc[i][j], 0, 0, 0);
      }
  }

  // epilogue: store C (f16) + fused exp column partial sums (of the f16-rounded value)
  float csum[8];
  #pragma unroll
  for (int j = 0; j < 8; ++j) csum[j] = 0.f;
  #pragma unroll
  for (int i = 0; i < 2; ++i) {
    const int rbase = m0 + i * 16 + kg * 4;
    #pragma unroll
    for (int j = 0; j < 8; ++j) {
      if (!cval[j]) continue;
      const int col = n0 + j * 16 + lr;
      #pragma unroll
      for (int q = 0; q < 4; ++q) {
        const _Float16 h = (_Float16)acc[i][j][q];
        C[(size_t)(rbase + q) * NPROT + col] = h;
        csum[j] += __expf((float)h * INV_EPS);
      }
    }
  }
  const int slot = blockIdx.y * 4 + wid;
  #pragma unroll
  for (int j = 0; j < 8; ++j) {
    float v = csum[j];
    v += __shfl_xor(v, 16, 64);
    v += __shfl_xor(v, 32, 64);
    if (lane < 16) {
      const int col = n0 + j * 16 + lane;
      if (col < Nb) colpart[(size_t)slot * PLD + col] = v;
    }
  }
}

// ---------- Sinkhorn reductions (f16 big) ----------
// column sums (over n) of exp(out*20)*C[n] -> partial; 4 cols per thread
__global__ __launch_bounds__(256) void k_colsum_part(const _Float16* __restrict__ big,
                                                     const float* __restrict__ Cvec,
                                                     float* __restrict__ part) {
  const int k4 = (blockIdx.x * 256 + threadIdx.x) * 4;
  if (k4 >= NPROT) return;
  const int n0 = blockIdx.y * (NROWS / NSPLIT);
  const int n1 = n0 + NROWS / NSPLIT;
  float s[4] = {0.f, 0.f, 0.f, 0.f};
  for (int n = n0; n < n1; ++n) {
    const f16x4 v = *reinterpret_cast<const f16x4*>(big + (size_t)n * NPROT + k4);
    const float c = Cvec[n];
    #pragma unroll
    for (int e = 0; e < 4; ++e) s[e] = fmaf(__expf((float)v[e] * INV_EPS), c, s[e]);
  }
  float4 w = make_float4(s[0], s[1], s[2], s[3]);
  *reinterpret_cast<float4*>(part + (size_t)blockIdx.y * PLD + k4) = w;
}

__global__ void k_colsum_fin(const float* __restrict__ part, int nslots,
                             float* __restrict__ R) {
  const int k = blockIdx.x * 256 + threadIdx.x;
  if (k >= NPROT) return;
  float s = 0.f;
  for (int nb = 0; nb < nslots; ++nb) s += part[(size_t)nb * PLD + k];
  R[k] = 1.0f / s;
}

// row sums (over k) of exp(out*20)*R[k] -> C[n] = 1/sum; vec8 loads (5000 = 625*8)
__global__ __launch_bounds__(256) void k_rowsum(const _Float16* __restrict__ big,
                                                const float* __restrict__ R,
                                                float* __restrict__ Cout) {
  const int n = blockIdx.x;
  const _Float16* row = big + (size_t)n * NPROT;
  float s = 0.f;
  for (int idx = threadIdx.x; idx < NPROT / 8; idx += 256) {
    const f16x8 v = *reinterpret_cast<const f16x8*>(row + idx * 8);
    const float4 r0 = *reinterpret_cast<const float4*>(R + idx * 8);
    const float4 r1 = *reinterpret_cast<const float4*>(R + idx * 8 + 4);
    s = fmaf(__expf((float)v[0] * INV_EPS), r0.x, s);
    s = fmaf(__expf((float)v[1] * INV_EPS), r0.y, s);
    s = fmaf(__expf((float)v[2] * INV_EPS), r0.z, s);
    s = fmaf(__expf((float)v[3] * INV_EPS), r0.w, s);
    s = fmaf(__expf((float)v[4] * INV_EPS), r1.x, s);
    s = fmaf(__expf((float)v[5] * INV_EPS), r1.y, s);
    s = fmaf(__expf((float)v[6] * INV_EPS), r1.z, s);
    s = fmaf(__expf((float)v[7] * INV_EPS), r1.w, s);
  }
  const float sT = blockReduceSum(s);
  if (threadIdx.x == 0) Cout[n] = 1.0f / sT;
}

// ---------- top-10 per row over the 50 in-class protos ----------
__global__ __launch_bounds__(256) void k_top10(const _Float16* __restrict__ out1,
                                               const float* __restrict__ R3,
                                               const int* __restrict__ targets,
                                               int* __restrict__ idx10,
                                               float* __restrict__ wsel) {
  const int n = blockIdx.x * 256 + threadIdx.x;
  if (n >= NROWS) return;
  const int c = targets[n & (BATCH - 1)];
  float tv[TOPK];
  int   tj[TOPK];
  #pragma unroll
  for (int i = 0; i < TOPK; ++i) { tv[i] = -1.0f; tj[i] = 0; }
  for (int j = 0; j < CACHE_SIZE; ++j) {
    const int k = c + j * NUM_CLASSES;
    float cv = __expf((float)out1[(size_t)n * NPROT + k] * INV_EPS) * R3[k];
    int cj = j;
    #pragma unroll
    for (int p = 0; p < TOPK; ++p) {   // stable bubble-insert (ties -> lower index first)
      if (cv > tv[p]) {
        const float ft = tv[p]; tv[p] = cv; cv = ft;
        const int   it = tj[p]; tj[p] = cj; cj = it;
      }
    }
  }
  float s = 0.f;
  #pragma unroll
  for (int i = 0; i < TOPK; ++i) s += tv[i];
  s = fmaxf(s, 1e-12f);
  for (int j = 0; j < CACHE_SIZE; ++j) wsel[(size_t)n * CACHE_SIZE + j] = 0.f;
  #pragma unroll
  for (int i = 0; i < TOPK; ++i) {
    wsel[(size_t)n * CACHE_SIZE + tj[i]] = tv[i] / s;
    idx10[n * TOPK + i] = c + tj[i] * NUM_CLASSES;
  }
}

// ---------- class counts + prefix (deterministic) ----------
__global__ void k_counts(const int* __restrict__ targets, int* __restrict__ classbase) {
  __shared__ int t[BATCH];
  __shared__ int cnt[NUM_CLASSES];
  for (int i = threadIdx.x; i < BATCH; i += 128) t[i] = targets[i];
  __syncthreads();
  if (threadIdx.x < NUM_CLASSES) {
    int m = 0;
    for (int b = 0; b < BATCH; ++b) m += (t[b] == (int)threadIdx.x);
    cnt[threadIdx.x] = 2 * m;
  }
  __syncthreads();
  if (threadIdx.x == 0) {
    int s = 0;
    for (int c = 0; c < NUM_CLASSES; ++c) { classbase[c] = s; s += cnt[c]; }
    classbase[NUM_CLASSES] = s;
  }
}

// ---------- rank-based rowlist: row v*B+b -> base[c] + v*cnt_c + rank_b ----------
__global__ __launch_bounds__(256) void k_rowlist(const int* __restrict__ targets,
                                                 const int* __restrict__ classbase,
                                                 int* __restrict__ rowlist) {
  __shared__ int t[BATCH];
  for (int i = threadIdx.x; i < BATCH; i += 256) t[i] = targets[i];
  __syncthreads();
  const int b = blockIdx.x * 256 + threadIdx.x;   // 0..2047
  const int c = t[b];
  int rank = 0;
  for (int i = 0; i < b; ++i) rank += (t[i] == c);
  const int base = classbase[c];
  const int cnt  = (classbase[c + 1] - base) >> 1;
  rowlist[base + rank] = b;                 // v=0 rows first (ascending b)
  rowlist[base + cnt + rank] = BATCH + b;   // then v=1 rows
}

// ---------- update_features (gather, deterministic order) ----------
__global__ __launch_bounds__(128) void k_uf(const float* __restrict__ feats,
                                            const float* __restrict__ wsel,
                                            const int* __restrict__ rowlist,
                                            const int* __restrict__ classbase,
                                            float* __restrict__ uf) {
  const int k = blockIdx.x;
  const int d = threadIdx.x;
  const int c = k % NUM_CLASSES;
  const int j = k / NUM_CLASSES;
  const int b0 = classbase[c], b1 = classbase[c + 1];
  float acc = 0.f;
  for (int ii = b0; ii < b1; ++ii) {
    const int n = rowlist[ii];
    const float wv = wsel[(size_t)n * CACHE_SIZE + j];
    if (wv != 0.f) acc = fmaf(wv, feats[(size_t)n * FD + d], acc);
  }
  uf[(size_t)k * FD + d] = acc;
}

// ---------- proto update + per-proto sim; emits normalized protos2 as bf16 hi/lo ----------
__global__ __launch_bounds__(128) void k_protoupd(const float* __restrict__ protos,
                                                  const float* __restrict__ uf,
                                                  short* __restrict__ pnhi,
                                                  short* __restrict__ pnlo,
                                                  float* __restrict__ simbuf) {
  const int k = blockIdx.x;
  const int d = threadIdx.x;
  const float p = protos[(size_t)k * FD + d];
  const float u = uf[(size_t)k * FD + d];
  const float pnew = PROTO_M * p + (1.0f - PROTO_M) * u;
  const float spp = blockReduceSum(p * p);
  const float suu = blockReduceSum(u * u);
  const float sup = blockReduceSum(u * p);
  const float snn = blockReduceSum(pnew * pnew);
  const float x = pnew / fmaxf(sqrtf(snn), 1e-12f);
  const short h = f2bf(x);
  pnhi[(size_t)k * FD + d] = h;
  pnlo[(size_t)k * FD + d] = f2bf(x - bf2f(h));
  if (d == 0)
    simbuf[k] = sup / (fmaxf(sqrtf(suu), 1e-12f) * fmaxf(sqrtf(spp), 1e-12f));
}

__global__ void k_tau(const float* __restrict__ simbuf, float* __restrict__ scalars) {
  float s = 0.f;
  for (int k = threadIdx.x; k < NPROT; k += 256) s += simbuf[k];
  s = blockReduceSum(s);
  if (threadIdx.x == 0) {
    const float sim_mean = s / (float)NPROT;
    scalars[0] = (1.0f + (0.5f - sim_mean)) * 0.4f;   // tau
  }
}

// ---------- mle per-row: neg - pos (f16 big, vec8) ----------
__global__ __launch_bounds__(256) void k_mle(const _Float16* __restrict__ out2,
                                             const float* __restrict__ R3,
                                             const int* __restrict__ targets,
                                             const int* __restrict__ idx10,
                                             const float* __restrict__ beta_ptr,
                                             float* __restrict__ rowres) {
  const int n = blockIdx.x;
  const int c = targets[n & (BATCH - 1)];
  const float beta = beta_ptr[0];
  int id[TOPK];
  #pragma unroll
  for (int i = 0; i < TOPK; ++i) id[i] = idx10[n * TOPK + i];
  const _Float16* row = out2 + (size_t)n * NPROT;
  float se = 0.f, swl = 0.f, sw = 0.f;
  for (int idx = threadIdx.x; idx < NPROT / 8; idx += 256) {
    const f16x8 v = *reinterpret_cast<const f16x8*>(row + idx * 8);
    #pragma unroll
    for (int e = 0; e < 8; ++e) {
      const int k = idx * 8 + e;
      const float o = (float)v[e];
      const float x = o * INV_TEMP;
      const float l = fmaxf(x, 0.f) + log1pf(__expf(-fabsf(x)));   // softplus
      float total;
      if (k % NUM_CLASSES == c) {
        total = l;
        bool sel = false;
        #pragma unroll
        for (int i = 0; i < TOPK; ++i) sel = sel || (id[i] == k);
        if (sel) {
          const float w2 = __expf(o * INV_EPS) * R3[k];
          swl += w2 * l;
          sw  += w2;
        }
      } else {
        const float imp = __powf(l + 1e-10f, beta);
        total = imp * l;
      }
      se += __expf(total);
    }
  }
  const float seT  = blockReduceSum(se);
  const float swlT = blockReduceSum(swl);
  const float swT  = blockReduceSum(sw);
  if (threadIdx.x == 0) {
    const float neg = __logf(seT);
    const float pos = swlT / fmaxf(swT, 1e-12f);
    rowres[n] = neg - pos;
  }
}

// ---------- proto contrast via MFMA, fused exp/logsum epilogue ----------
__global__ __launch_bounds__(256) void k_pcon_mfma(
    const short* __restrict__ Phi, const short* __restrict__ Plo,
    const float* __restrict__ scalars,
    float* __restrict__ part_neg, float* __restrict__ part_pos) {
  const int tid  = threadIdx.x;
  const int wid  = tid >> 6;
  const int lane = tid & 63;
  const int lr   = lane & 15;
  const int kg   = lane >> 4;
  const int k0   = blockIdx.y * 128 + wid * 32;   // rows (protos "k")
  const int l0   = blockIdx.x * 128;              // cols (protos "l")
  const float invtau = 1.0f / scalars[0];

  f32x4 acc[2][8];
  #pragma unroll
  for (int i = 0; i < 2; ++i)
    #pragma unroll
    for (int j = 0; j < 8; ++j) acc[i][j] = (f32x4){0.f, 0.f, 0.f, 0.f};

  int rowa[2];
  #pragma unroll
  for (int i = 0; i < 2; ++i) {
    const int r = k0 + i * 16 + lr;
    rowa[i] = (r < NPROT) ? r : (NPROT - 1);
  }
  int colc[8]; bool cval[8];
  #pragma unroll
  for (int j = 0; j < 8; ++j) {
    const int col = l0 + j * 16 + lr;
    cval[j] = (col < NPROT);
    colc[j] = cval[j] ? col : (NPROT - 1);
  }

  #pragma unroll
  for (int kk = 0; kk < 4; ++kk) {
    const int kb = kk * 32 + kg * 8;
    bf16x8 ah[2], al[2], bh[8], bl[8];
    #pragma unroll
    for (int i = 0; i < 2; ++i) {
      const size_t off = (size_t)rowa[i] * FD + kb;
      ah[i] = *reinterpret_cast<const bf16x8*>(Phi + off);
      al[i] = *reinterpret_cast<const bf16x8*>(Plo + off);
    }
    #pragma unroll
    for (int j = 0; j < 8; ++j) {
      const size_t off = (size_t)colc[j] * FD + kb;
      bh[j] = *reinterpret_cast<const bf16x8*>(Phi + off);
      bl[j] = *reinterpret_cast<const bf16x8*>(Plo + off);
    }
    #pragma unroll
    for (int i = 0; i < 2; ++i)
      #pragma unroll
      for (int j = 0; j < 8; ++j) {
        acc[i][j] = __builtin_amdgcn_mfma_f32_16x16x32_bf16(ah[i], bh[j], acc[i][j], 0, 0, 0);
        acc[i][j] = __builtin_amdgcn_mfma_f32_16x16x32_bf16(ah[i], bl[j], acc[i][j], 0, 0, 0);
        acc[i][j] = __builtin_amdgcn_mfma_f32_16x16x32_bf16(al[i], bh[j], acc[i][j], 0, 0, 0);
      }
  }

  // epilogue
  int ccls[8];
  #pragma unroll
  for (int j = 0; j < 8; ++j) ccls[j] = (l0 + j * 16 + lr) % NUM_CLASSES;

  #pragma unroll
  for (int i = 0; i < 2; ++i) {
    float sneg[4] = {0.f, 0.f, 0.f, 0.f};
    float spos[4] = {0.f, 0.f, 0.f, 0.f};
    const int rbase = k0 + i * 16 + kg * 4;
    #pragma unroll
    for (int q = 0; q < 4; ++q) {
      const int rg = rbase + q;
      if (rg >= NPROT) continue;
      const int rcls = rg % NUM_CLASSES;
      #pragma unroll
      for (int j = 0; j < 8; ++j) {
        const int cg = l0 + j * 16 + lr;
        if (!cval[j] || cg == rg) continue;
        const float lg = fmaf(acc[i][j][q], invtau, -invtau);
        sneg[q] += __expf(lg);
        if (ccls[j] == rcls) spos[q] += lg;
      }
    }
    #pragma unroll
    for (int q = 0; q < 4; ++q) {
      float sn = sneg[q], sp = spos[q];
      #pragma unroll
      for (int o = 8; o > 0; o >>= 1) {
        sn += __shfl_xor(sn, o, 64);
        sp += __shfl_xor(sp, o, 64);
      }
      if (lr == 0) {
        const int rg = rbase + q;
        if (rg < NPROT) {
          part_neg[(size_t)blockIdx.x * PLD + rg] = sn;
          part_pos[(size_t)blockIdx.x * PLD + rg] = sp;
        }
      }
    }
  }
}

__global__ void k_pcon_fin(const float* __restrict__ part_neg,
                           const float* __restrict__ part_pos,
                           float* __restrict__ pconbuf) {
  const int k = blockIdx.x * 256 + threadIdx.x;
  if (k >= NPROT) return;
  float sn = 0.f, sp = 0.f;
  #pragma unroll 4
  for (int b = 0; b < 40; ++b) {
    sn += part_neg[(size_t)b * PLD + k];
    sp += part_pos[(size_t)b * PLD + k];
  }
  pconbuf[k] = __logf(sn) - sp * (1.0f / (float)(CACHE_SIZE - 1));
}

__global__ void k_final(const float* __restrict__ rowres,
                        const float* __restrict__ pconbuf,
                        float* __restrict__ outp) {
  float s1 = 0.f, s2 = 0.f;
  for (int i = threadIdx.x; i < NROWS; i += 256) s1 += rowres[i];
  for (int i = threadIdx.x; i < NPROT; i += 256) s2 += pconbuf[i];
  s1 = blockReduceSum(s1);
  s2 = blockReduceSum(s2);
  if (threadIdx.x == 0) outp[0] = s1 / (float)NROWS + s2 / (float)NPROT;
}

// ---------- host ----------
extern "C" void kernel_launch(void* const* d_in, const int* in_sizes, int n_in,
                              void* d_out, int out_size, void* d_ws, size_t ws_size,
                              hipStream_t stream) {
  (void)in_sizes; (void)n_in; (void)out_size; (void)ws_size;
  const float* features = (const float*)d_in[0];
  const int*   targets  = (const int*)d_in[1];
  const float* beta     = (const float*)d_in[2];
  const float* protos   = (const float*)d_in[3];
  float* outp = (float*)d_out;

  char* basep = (char*)d_ws;
  size_t off = 0;
  auto alloc = [&](size_t bytes) -> void* {
    void* p = basep + off;
    off = (off + bytes + 255) & ~(size_t)255;
    return p;
  };
  _Float16* big  = (_Float16*)alloc((size_t)NROWS * NPROT * 2);   // 40.96 MB
  float* feats   = (float*)alloc((size_t)NROWS * FD * 4);
  short* fhi     = (short*)alloc((size_t)NROWS * FD * 2);
  short* flo     = (short*)alloc((size_t)NROWS * FD * 2);
  short* phi     = (short*)alloc((size_t)NPROT * FD * 2);      // protos, then reused as pn
  short* plo     = (short*)alloc((size_t)NPROT * FD * 2);
  float* part    = (float*)alloc((size_t)128 * PLD * 4);       // GEMM colsum slots (128) >= NSPLIT
  float* Rk      = (float*)alloc(NPROT * 4);
  float* Cn      = (float*)alloc(NROWS * 4);
  int*   idx10   = (int*)alloc(NROWS * TOPK * 4);
  float* wsel    = (float*)alloc((size_t)NROWS * CACHE_SIZE * 4);
  int*   rowlist = (int*)alloc(NROWS * 4);
  int*   classbase = (int*)alloc((NUM_CLASSES + 1) * 4);
  float* uf      = (float*)alloc((size_t)NPROT * FD * 4);
  float* simbuf  = (float*)alloc(NPROT * 4);
  float* scalars = (float*)alloc(64);
  float* rowres  = (float*)alloc(NROWS * 4);
  float* pconbuf = (float*)alloc(NPROT * 4);
  float* pneg    = (float*)alloc((size_t)40 * PLD * 4);
  float* ppos    = (float*)alloc((size_t)40 * PLD * 4);

  k_build_feats<<<512, 256, 0, stream>>>(features, feats, fhi, flo);
  k_split<<<(NPROT * FD / 4 + 255) / 256, 256, 0, stream>>>(protos, NPROT * FD / 4, phi, plo);
  k_counts<<<1, 128, 0, stream>>>(targets, classbase);
  k_rowlist<<<BATCH / 256, 256, 0, stream>>>(targets, classbase, rowlist);

  // GEMM1 (fused colsum pass 1) + rest of sinkhorn1
  k_gemm_mfma<<<dim3(40, 32), 256, 0, stream>>>(fhi, flo, phi, plo, NPROT, big, part);
  k_colsum_fin<<<20, 256, 0, stream>>>(part, 128, Rk);                 // R1
  k_rowsum<<<NROWS, 256, 0, stream>>>(big, Rk, Cn);                    // C1
  k_colsum_part<<<dim3(5, NSPLIT), 256, 0, stream>>>(big, Cn, part);
  k_colsum_fin<<<20, 256, 0, stream>>>(part, NSPLIT, Rk);              // R2
  k_rowsum<<<NROWS, 256, 0, stream>>>(big, Rk, Cn);                    // C2
  k_colsum_part<<<dim3(5, NSPLIT), 256, 0, stream>>>(big, Cn, part);
  k_colsum_fin<<<20, 256, 0, stream>>>(part, NSPLIT, Rk);              // R3

  k_top10<<<16, 256, 0, stream>>>(big, Rk, targets, idx10, wsel);
  k_uf<<<NPROT, 128, 0, stream>>>(feats, wsel, rowlist, classbase, uf);
  k_protoupd<<<NPROT, 128, 0, stream>>>(protos, uf, phi, plo, simbuf); // phi/plo now hold pn
  k_tau<<<1, 256, 0, stream>>>(simbuf, scalars);

  // GEMM2 (fused colsum pass 1) + rest of sinkhorn2
  k_gemm_mfma<<<dim3(40, 32), 256, 0, stream>>>(fhi, flo, phi, plo, NPROT, big, part);
  k_colsum_fin<<<20, 256, 0, stream>>>(part, 128, Rk);                 // R1'
  k_rowsum<<<NROWS, 256, 0, stream>>>(big, Rk, Cn);
  k_colsum_part<<<dim3(5, NSPLIT), 256, 0, stream>>>(big, Cn, part);
  k_colsum_fin<<<20, 256, 0, stream>>>(part, NSPLIT, Rk);              // R2'
  k_rowsum<<<NROWS, 256, 0, stream>>>(big, Rk, Cn);
  k_colsum_part<<<dim3(5, NSPLIT), 256, 0, stream>>>(big, Cn, part);
  k_colsum_fin<<<20, 256, 0, stream>>>(part, NSPLIT, Rk);              // R3'

  k_mle<<<NROWS, 256, 0, stream>>>(big, Rk, targets, idx10, beta, rowres);
  k_pcon_mfma<<<dim3(40, 40), 256, 0, stream>>>(phi, plo, scalars, pneg, ppos);
  k_pcon_fin<<<20, 256, 0, stream>>>(pneg, ppos, pconbuf);
  k_final<<<1, 256, 0, stream>>>(rowres, pconbuf, outp);
}

// Round 5
// 622.932 us; speedup vs baseline: 1.1914x; 1.1914x over previous
//
#include <hip/hip_runtime.h>
#include <math.h>

constexpr int NUM_CLASSES = 100;
constexpr int CACHE_SIZE  = 50;
constexpr int NPROT       = 5000;   // NUM_CLASSES*CACHE_SIZE
constexpr int FD          = 128;
constexpr int BATCH       = 2048;
constexpr int NROWS       = 4096;   // BATCH*NVIEWS
constexpr int TOPK        = 10;
constexpr float INV_EPS   = 20.0f;  // 1/0.05
constexpr float INV_TEMP  = 10.0f;  // 1/0.1
constexpr float PROTO_M   = 0.99f;
constexpr int NSPLIT      = 64;     // colsum row-splits (320 blocks)
constexpr int PLD         = 5120;   // padded leading dim for partial buffers

typedef __attribute__((ext_vector_type(8))) short bf16x8;
typedef __attribute__((ext_vector_type(4))) float f32x4;
typedef __attribute__((ext_vector_type(4))) _Float16 f16x4;
typedef __attribute__((ext_vector_type(8))) _Float16 f16x8;

// ---------- helpers ----------
__device__ __forceinline__ float blockReduceSum(float v) {
  __shared__ float tmp[8];
  const int lane = threadIdx.x & 63;
  const int wid  = threadIdx.x >> 6;
  #pragma unroll
  for (int o = 32; o > 0; o >>= 1) v += __shfl_down(v, o, 64);
  __syncthreads();               // protect tmp across repeated calls
  if (lane == 0) tmp[wid] = v;
  __syncthreads();
  const int nw = (blockDim.x + 63) >> 6;
  float s = 0.f;
  for (int i = 0; i < nw; ++i) s += tmp[i];
  return s;                      // broadcast to all threads
}

__device__ __forceinline__ short f2bf(float x) {   // RNE fp32 -> bf16 bits
  union { float f; unsigned u; } v; v.f = x;
  const unsigned r = v.u + 0x7fffu + ((v.u >> 16) & 1u);
  return (short)(r >> 16);
}
__device__ __forceinline__ float bf2f(short h) {
  union { float f; unsigned u; } v; v.u = ((unsigned)(unsigned short)h) << 16;
  return v.f;
}

// fast softplus(x) using hw exp/log (v_exp_f32 / v_log_f32)
__device__ __forceinline__ float fast_softplus(float x) {
  return fmaxf(x, 0.f) + __logf(1.f + __expf(-fabsf(x)));
}

// ---------- build feats (+ bf16 hi/lo split): feats[v*B+b] = features[b,v,:] ----------
__global__ void k_build_feats(const float* __restrict__ features,
                              float* __restrict__ feats,
                              short* __restrict__ fhi, short* __restrict__ flo) {
  const int t = blockIdx.x * blockDim.x + threadIdx.x;   // one float4 each
  if (t >= NROWS * (FD / 4)) return;
  const int n  = t >> 5;            // / (128/4)
  const int d4 = (t & 31) << 2;
  const int b  = n & (BATCH - 1);
  const int v  = n >> 11;
  const float4 src = *reinterpret_cast<const float4*>(features + ((size_t)b * 2 + v) * FD + d4);
  *reinterpret_cast<float4*>(feats + (size_t)n * FD + d4) = src;
  short4 h, l;
  h.x = f2bf(src.x); l.x = f2bf(src.x - bf2f(h.x));
  h.y = f2bf(src.y); l.y = f2bf(src.y - bf2f(h.y));
  h.z = f2bf(src.z); l.z = f2bf(src.z - bf2f(h.z));
  h.w = f2bf(src.w); l.w = f2bf(src.w - bf2f(h.w));
  *reinterpret_cast<short4*>(fhi + (size_t)n * FD + d4) = h;
  *reinterpret_cast<short4*>(flo + (size_t)n * FD + d4) = l;
}

// ---------- split any fp32 [n][128] matrix into bf16 hi/lo ----------
__global__ void k_split(const float* __restrict__ src, int nelem4,
                        short* __restrict__ hi, short* __restrict__ lo) {
  const int t = blockIdx.x * blockDim.x + threadIdx.x;
  if (t >= nelem4) return;
  const float4 v = *reinterpret_cast<const float4*>(src + (size_t)t * 4);
  short4 h, l;
  h.x = f2bf(v.x); l.x = f2bf(v.x - bf2f(h.x));
  h.y = f2bf(v.y); l.y = f2bf(v.y - bf2f(h.y));
  h.z = f2bf(v.z); l.z = f2bf(v.z - bf2f(h.z));
  h.w = f2bf(v.w); l.w = f2bf(v.w - bf2f(h.w));
  *reinterpret_cast<short4*>(hi + (size_t)t * 4) = h;
  *reinterpret_cast<short4*>(lo + (size_t)t * 4) = l;
}

// ---------- MFMA GEMM: C[m][n] = sum_d A[m][d]*B[n][d], split-bf16 3-product ----------
// Output C stored f16. Fused epilogue: colpart[slot][n] = sum_m exp(C_f16*20)
// per (block-row, wave) slot (slot = blockIdx.y*4 + wid, 128 slots total).
__global__ __launch_bounds__(256) void k_gemm_mfma(
    const short* __restrict__ Ahi, const short* __restrict__ Alo,
    const short* __restrict__ Bhi, const short* __restrict__ Blo,
    int Nb, _Float16* __restrict__ C, float* __restrict__ colpart) {
  const int tid  = threadIdx.x;
  const int wid  = tid >> 6;
  const int lane = tid & 63;
  const int lr   = lane & 15;      // fragment row/col
  const int kg   = lane >> 4;      // k-group (0..3)
  const int m0   = blockIdx.y * 128 + wid * 32;
  const int n0   = blockIdx.x * 128;

  f32x4 acc[2][8];
  #pragma unroll
  for (int i = 0; i < 2; ++i)
    #pragma unroll
    for (int j = 0; j < 8; ++j) acc[i][j] = (f32x4){0.f, 0.f, 0.f, 0.f};

  int colc[8]; bool cval[8];
  #pragma unroll
  for (int j = 0; j < 8; ++j) {
    const int col = n0 + j * 16 + lr;
    cval[j] = (col < Nb);
    colc[j] = cval[j] ? col : (Nb - 1);
  }
  const bf16x8 bz = {0, 0, 0, 0, 0, 0, 0, 0};

  #pragma unroll
  for (int kk = 0; kk < 4; ++kk) {
    const int kb = kk * 32 + kg * 8;
    bf16x8 ah[2], al[2], bh[8], bl[8];
    #pragma unroll
    for (int i = 0; i < 2; ++i) {
      const size_t off = (size_t)(m0 + i * 16 + lr) * FD + kb;
      ah[i] = *reinterpret_cast<const bf16x8*>(Ahi + off);
      al[i] = *reinterpret_cast<const bf16x8*>(Alo + off);
    }
    #pragma unroll
    for (int j = 0; j < 8; ++j) {
      const size_t off = (size_t)colc[j] * FD + kb;
      bh[j] = cval[j] ? *reinterpret_cast<const bf16x8*>(Bhi + off) : bz;
      bl[j] = cval[j] ? *reinterpret_cast<const bf16x8*>(Blo + off) : bz;
    }
    #pragma unroll
    for (int i = 0; i < 2; ++i)
      #pragma unroll
      for (int j = 0; j < 8; ++j) {
        acc[i][j] = __builtin_amdgcn_mfma_f32_16x16x32_bf16(ah[i], bh[j], acc[i][j], 0, 0, 0);
        acc[i][j] = __builtin_amdgcn_mfma_f32_16x16x32_bf16(ah[i], bl[j], acc[i][j], 0, 0, 0);
        acc[i][j] = __builtin_amdgcn_mfma_f32_16x16x32_bf16(al[i], bh[j], acc[i][j], 0, 0, 0);
      }
  }

  // epilogue: store C (f16) + fused exp column partial sums (of the f16-rounded value)
  float csum[8];
  #pragma unroll
  for (int j = 0; j < 8; ++j) csum[j] = 0.f;
  #pragma unroll
  for (int i = 0; i < 2; ++i) {
    const int rbase = m0 + i * 16 + kg * 4;
    #pragma unroll
    for (int j = 0; j < 8; ++j) {
      if (!cval[j]) continue;
      const int col = n0 + j * 16 + lr;
      #pragma unroll
      for (int q = 0; q < 4; ++q) {
        const _Float16 h = (_Float16)acc[i][j][q];
        C[(size_t)(rbase + q) * NPROT + col] = h;
        csum[j] += __expf((float)h * INV_EPS);
      }
    }
  }
  const int slot = blockIdx.y * 4 + wid;
  #pragma unroll
  for (int j = 0; j < 8; ++j) {
    float v = csum[j];
    v += __shfl_xor(v, 16, 64);
    v += __shfl_xor(v, 32, 64);
    if (lane < 16) {
      const int col = n0 + j * 16 + lane;
      if (col < Nb) colpart[(size_t)slot * PLD + col] = v;
    }
  }
}

// ---------- Sinkhorn reductions (f16 big) ----------
// column sums (over n) of exp(out*20)*C[n] -> partial; 4 cols per thread
__global__ __launch_bounds__(256) void k_colsum_part(const _Float16* __restrict__ big,
                                                     const float* __restrict__ Cvec,
                                                     float* __restrict__ part) {
  const int k4 = (blockIdx.x * 256 + threadIdx.x) * 4;
  if (k4 >= NPROT) return;
  const int n0 = blockIdx.y * (NROWS / NSPLIT);
  const int n1 = n0 + NROWS / NSPLIT;
  float s[4] = {0.f, 0.f, 0.f, 0.f};
  for (int n = n0; n < n1; ++n) {
    const f16x4 v = *reinterpret_cast<const f16x4*>(big + (size_t)n * NPROT + k4);
    const float c = Cvec[n];
    #pragma unroll
    for (int e = 0; e < 4; ++e) s[e] = fmaf(__expf((float)v[e] * INV_EPS), c, s[e]);
  }
  float4 w = make_float4(s[0], s[1], s[2], s[3]);
  *reinterpret_cast<float4*>(part + (size_t)blockIdx.y * PLD + k4) = w;
}

__global__ void k_colsum_fin(const float* __restrict__ part, int nslots,
                             float* __restrict__ R) {
  const int k = blockIdx.x * 256 + threadIdx.x;
  if (k >= NPROT) return;
  float s = 0.f;
  for (int nb = 0; nb < nslots; ++nb) s += part[(size_t)nb * PLD + k];
  R[k] = 1.0f / s;
}

// row sums (over k) of exp(out*20)*R[k] -> C[n] = 1/sum; vec8 loads (5000 = 625*8)
__global__ __launch_bounds__(256) void k_rowsum(const _Float16* __restrict__ big,
                                                const float* __restrict__ R,
                                                float* __restrict__ Cout) {
  const int n = blockIdx.x;
  const _Float16* row = big + (size_t)n * NPROT;
  float s = 0.f;
  for (int idx = threadIdx.x; idx < NPROT / 8; idx += 256) {
    const f16x8 v = *reinterpret_cast<const f16x8*>(row + idx * 8);
    const float4 r0 = *reinterpret_cast<const float4*>(R + idx * 8);
    const float4 r1 = *reinterpret_cast<const float4*>(R + idx * 8 + 4);
    s = fmaf(__expf((float)v[0] * INV_EPS), r0.x, s);
    s = fmaf(__expf((float)v[1] * INV_EPS), r0.y, s);
    s = fmaf(__expf((float)v[2] * INV_EPS), r0.z, s);
    s = fmaf(__expf((float)v[3] * INV_EPS), r0.w, s);
    s = fmaf(__expf((float)v[4] * INV_EPS), r1.x, s);
    s = fmaf(__expf((float)v[5] * INV_EPS), r1.y, s);
    s = fmaf(__expf((float)v[6] * INV_EPS), r1.z, s);
    s = fmaf(__expf((float)v[7] * INV_EPS), r1.w, s);
  }
  const float sT = blockReduceSum(s);
  if (threadIdx.x == 0) Cout[n] = 1.0f / sT;
}

// ---------- top-10 per row over the 50 in-class protos ----------
__global__ __launch_bounds__(256) void k_top10(const _Float16* __restrict__ out1,
                                               const float* __restrict__ R3,
                                               const int* __restrict__ targets,
                                               int* __restrict__ idx10,
                                               float* __restrict__ wsel) {
  const int n = blockIdx.x * 256 + threadIdx.x;
  if (n >= NROWS) return;
  const int c = targets[n & (BATCH - 1)];
  float tv[TOPK];
  int   tj[TOPK];
  #pragma unroll
  for (int i = 0; i < TOPK; ++i) { tv[i] = -1.0f; tj[i] = 0; }
  for (int j = 0; j < CACHE_SIZE; ++j) {
    const int k = c + j * NUM_CLASSES;
    float cv = __expf((float)out1[(size_t)n * NPROT + k] * INV_EPS) * R3[k];
    int cj = j;
    #pragma unroll
    for (int p = 0; p < TOPK; ++p) {   // stable bubble-insert (ties -> lower index first)
      if (cv > tv[p]) {
        const float ft = tv[p]; tv[p] = cv; cv = ft;
        const int   it = tj[p]; tj[p] = cj; cj = it;
      }
    }
  }
  float s = 0.f;
  #pragma unroll
  for (int i = 0; i < TOPK; ++i) s += tv[i];
  s = fmaxf(s, 1e-12f);
  for (int j = 0; j < CACHE_SIZE; ++j) wsel[(size_t)n * CACHE_SIZE + j] = 0.f;
  #pragma unroll
  for (int i = 0; i < TOPK; ++i) {
    wsel[(size_t)n * CACHE_SIZE + tj[i]] = tv[i] / s;
    idx10[n * TOPK + i] = c + tj[i] * NUM_CLASSES;
  }
}

// ---------- class counts + prefix (deterministic) ----------
__global__ void k_counts(const int* __restrict__ targets, int* __restrict__ classbase) {
  __shared__ int t[BATCH];
  __shared__ int cnt[NUM_CLASSES];
  for (int i = threadIdx.x; i < BATCH; i += 128) t[i] = targets[i];
  __syncthreads();
  if (threadIdx.x < NUM_CLASSES) {
    int m = 0;
    for (int b = 0; b < BATCH; ++b) m += (t[b] == (int)threadIdx.x);
    cnt[threadIdx.x] = 2 * m;
  }
  __syncthreads();
  if (threadIdx.x == 0) {
    int s = 0;
    for (int c = 0; c < NUM_CLASSES; ++c) { classbase[c] = s; s += cnt[c]; }
    classbase[NUM_CLASSES] = s;
  }
}

// ---------- rank-based rowlist: row v*B+b -> base[c] + v*cnt_c + rank_b ----------
__global__ __launch_bounds__(256) void k_rowlist(const int* __restrict__ targets,
                                                 const int* __restrict__ classbase,
                                                 int* __restrict__ rowlist) {
  __shared__ int t[BATCH];
  for (int i = threadIdx.x; i < BATCH; i += 256) t[i] = targets[i];
  __syncthreads();
  const int b = blockIdx.x * 256 + threadIdx.x;   // 0..2047
  const int c = t[b];
  int rank = 0;
  for (int i = 0; i < b; ++i) rank += (t[i] == c);
  const int base = classbase[c];
  const int cnt  = (classbase[c + 1] - base) >> 1;
  rowlist[base + rank] = b;                 // v=0 rows first (ascending b)
  rowlist[base + cnt + rank] = BATCH + b;   // then v=1 rows
}

// ---------- update_features (gather, deterministic order) ----------
__global__ __launch_bounds__(128) void k_uf(const float* __restrict__ feats,
                                            const float* __restrict__ wsel,
                                            const int* __restrict__ rowlist,
                                            const int* __restrict__ classbase,
                                            float* __restrict__ uf) {
  const int k = blockIdx.x;
  const int d = threadIdx.x;
  const int c = k % NUM_CLASSES;
  const int j = k / NUM_CLASSES;
  const int b0 = classbase[c], b1 = classbase[c + 1];
  float acc = 0.f;
  for (int ii = b0; ii < b1; ++ii) {
    const int n = rowlist[ii];
    const float wv = wsel[(size_t)n * CACHE_SIZE + j];
    if (wv != 0.f) acc = fmaf(wv, feats[(size_t)n * FD + d], acc);
  }
  uf[(size_t)k * FD + d] = acc;
}

// ---------- proto update + per-proto sim; emits normalized protos2 as bf16 hi/lo ----------
__global__ __launch_bounds__(128) void k_protoupd(const float* __restrict__ protos,
                                                  const float* __restrict__ uf,
                                                  short* __restrict__ pnhi,
                                                  short* __restrict__ pnlo,
                                                  float* __restrict__ simbuf) {
  const int k = blockIdx.x;
  const int d = threadIdx.x;
  const float p = protos[(size_t)k * FD + d];
  const float u = uf[(size_t)k * FD + d];
  const float pnew = PROTO_M * p + (1.0f - PROTO_M) * u;
  const float spp = blockReduceSum(p * p);
  const float suu = blockReduceSum(u * u);
  const float sup = blockReduceSum(u * p);
  const float snn = blockReduceSum(pnew * pnew);
  const float x = pnew / fmaxf(sqrtf(snn), 1e-12f);
  const short h = f2bf(x);
  pnhi[(size_t)k * FD + d] = h;
  pnlo[(size_t)k * FD + d] = f2bf(x - bf2f(h));
  if (d == 0)
    simbuf[k] = sup / (fmaxf(sqrtf(suu), 1e-12f) * fmaxf(sqrtf(spp), 1e-12f));
}

__global__ void k_tau(const float* __restrict__ simbuf, float* __restrict__ scalars) {
  float s = 0.f;
  for (int k = threadIdx.x; k < NPROT; k += 256) s += simbuf[k];
  s = blockReduceSum(s);
  if (threadIdx.x == 0) {
    const float sim_mean = s / (float)NPROT;
    scalars[0] = (1.0f + (0.5f - sim_mean)) * 0.4f;   // tau
  }
}

// ---------- mle per-row: neg - pos (f16 big, vec8) ----------
// Main loop: uniform negative-branch formula for ALL columns (no divergence).
// Phase 2: correct the 50 in-class columns (+exp(l) - exp(imp*l)) and do pos/topk.
__global__ __launch_bounds__(256) void k_mle(const _Float16* __restrict__ out2,
                                             const float* __restrict__ R3,
                                             const int* __restrict__ targets,
                                             const int* __restrict__ idx10,
                                             const float* __restrict__ beta_ptr,
                                             float* __restrict__ rowres) {
  const int n = blockIdx.x;
  const int c = targets[n & (BATCH - 1)];
  const float beta = beta_ptr[0];
  const bool bhalf = (beta == 0.5f);
  const _Float16* row = out2 + (size_t)n * NPROT;

  float se = 0.f;
  for (int idx = threadIdx.x; idx < NPROT / 8; idx += 256) {
    const f16x8 v = *reinterpret_cast<const f16x8*>(row + idx * 8);
    #pragma unroll
    for (int e = 0; e < 8; ++e) {
      const float x = (float)v[e] * INV_TEMP;
      const float l = fast_softplus(x);
      const float lb = l + 1e-10f;
      const float imp = bhalf ? sqrtf(lb) : __expf(beta * __logf(lb));
      se += __expf(imp * l);
    }
  }

  // correction + positive part over the 50 in-class columns
  float swl = 0.f, sw = 0.f;
  int id[TOPK];
  #pragma unroll
  for (int i = 0; i < TOPK; ++i) id[i] = idx10[n * TOPK + i];
  for (int j = threadIdx.x; j < CACHE_SIZE; j += 256) {
    const int k = c + j * NUM_CLASSES;
    const float o = (float)row[k];
    const float x = o * INV_TEMP;
    const float l = fast_softplus(x);
    const float lb = l + 1e-10f;
    const float imp = bhalf ? sqrtf(lb) : __expf(beta * __logf(lb));
    se += __expf(l) - __expf(imp * l);   // replace neg-formula term with true in-class term
    bool sel = false;
    #pragma unroll
    for (int i = 0; i < TOPK; ++i) sel = sel || (id[i] == k);
    if (sel) {
      const float w2 = __expf(o * INV_EPS) * R3[k];
      swl += w2 * l;
      sw  += w2;
    }
  }

  const float seT  = blockReduceSum(se);
  const float swlT = blockReduceSum(swl);
  const float swT  = blockReduceSum(sw);
  if (threadIdx.x == 0) {
    const float neg = __logf(seT);
    const float pos = swlT / fmaxf(swT, 1e-12f);
    rowres[n] = neg - pos;
  }
}

// ---------- proto contrast via MFMA, fused exp/logsum epilogue ----------
__global__ __launch_bounds__(256) void k_pcon_mfma(
    const short* __restrict__ Phi, const short* __restrict__ Plo,
    const float* __restrict__ scalars,
    float* __restrict__ part_neg, float* __restrict__ part_pos) {
  const int tid  = threadIdx.x;
  const int wid  = tid >> 6;
  const int lane = tid & 63;
  const int lr   = lane & 15;
  const int kg   = lane >> 4;
  const int k0   = blockIdx.y * 128 + wid * 32;   // rows (protos "k")
  const int l0   = blockIdx.x * 128;              // cols (protos "l")
  const float invtau = 1.0f / scalars[0];

  f32x4 acc[2][8];
  #pragma unroll
  for (int i = 0; i < 2; ++i)
    #pragma unroll
    for (int j = 0; j < 8; ++j) acc[i][j] = (f32x4){0.f, 0.f, 0.f, 0.f};

  int rowa[2];
  #pragma unroll
  for (int i = 0; i < 2; ++i) {
    const int r = k0 + i * 16 + lr;
    rowa[i] = (r < NPROT) ? r : (NPROT - 1);
  }
  int colc[8]; bool cval[8];
  #pragma unroll
  for (int j = 0; j < 8; ++j) {
    const int col = l0 + j * 16 + lr;
    cval[j] = (col < NPROT);
    colc[j] = cval[j] ? col : (NPROT - 1);
  }

  #pragma unroll
  for (int kk = 0; kk < 4; ++kk) {
    const int kb = kk * 32 + kg * 8;
    bf16x8 ah[2], al[2], bh[8], bl[8];
    #pragma unroll
    for (int i = 0; i < 2; ++i) {
      const size_t off = (size_t)rowa[i] * FD + kb;
      ah[i] = *reinterpret_cast<const bf16x8*>(Phi + off);
      al[i] = *reinterpret_cast<const bf16x8*>(Plo + off);
    }
    #pragma unroll
    for (int j = 0; j < 8; ++j) {
      const size_t off = (size_t)colc[j] * FD + kb;
      bh[j] = *reinterpret_cast<const bf16x8*>(Phi + off);
      bl[j] = *reinterpret_cast<const bf16x8*>(Plo + off);
    }
    #pragma unroll
    for (int i = 0; i < 2; ++i)
      #pragma unroll
      for (int j = 0; j < 8; ++j) {
        acc[i][j] = __builtin_amdgcn_mfma_f32_16x16x32_bf16(ah[i], bh[j], acc[i][j], 0, 0, 0);
        acc[i][j] = __builtin_amdgcn_mfma_f32_16x16x32_bf16(ah[i], bl[j], acc[i][j], 0, 0, 0);
        acc[i][j] = __builtin_amdgcn_mfma_f32_16x16x32_bf16(al[i], bh[j], acc[i][j], 0, 0, 0);
      }
  }

  // epilogue
  int ccls[8];
  #pragma unroll
  for (int j = 0; j < 8; ++j) ccls[j] = (l0 + j * 16 + lr) % NUM_CLASSES;

  #pragma unroll
  for (int i = 0; i < 2; ++i) {
    float sneg[4] = {0.f, 0.f, 0.f, 0.f};
    float spos[4] = {0.f, 0.f, 0.f, 0.f};
    const int rbase = k0 + i * 16 + kg * 4;
    #pragma unroll
    for (int q = 0; q < 4; ++q) {
      const int rg = rbase + q;
      if (rg >= NPROT) continue;
      const int rcls = rg % NUM_CLASSES;
      #pragma unroll
      for (int j = 0; j < 8; ++j) {
        const int cg = l0 + j * 16 + lr;
        if (!cval[j] || cg == rg) continue;
        const float lg = fmaf(acc[i][j][q], invtau, -invtau);
        sneg[q] += __expf(lg);
        if (ccls[j] == rcls) spos[q] += lg;
      }
    }
    #pragma unroll
    for (int q = 0; q < 4; ++q) {
      float sn = sneg[q], sp = spos[q];
      #pragma unroll
      for (int o = 8; o > 0; o >>= 1) {
        sn += __shfl_xor(sn, o, 64);
        sp += __shfl_xor(sp, o, 64);
      }
      if (lr == 0) {
        const int rg = rbase + q;
        if (rg < NPROT) {
          part_neg[(size_t)blockIdx.x * PLD + rg] = sn;
          part_pos[(size_t)blockIdx.x * PLD + rg] = sp;
        }
      }
    }
  }
}

__global__ void k_pcon_fin(const float* __restrict__ part_neg,
                           const float* __restrict__ part_pos,
                           float* __restrict__ pconbuf) {
  const int k = blockIdx.x * 256 + threadIdx.x;
  if (k >= NPROT) return;
  float sn = 0.f, sp = 0.f;
  #pragma unroll 4
  for (int b = 0; b < 40; ++b) {
    sn += part_neg[(size_t)b * PLD + k];
    sp += part_pos[(size_t)b * PLD + k];
  }
  pconbuf[k] = __logf(sn) - sp * (1.0f / (float)(CACHE_SIZE - 1));
}

__global__ void k_final(const float* __restrict__ rowres,
                        const float* __restrict__ pconbuf,
                        float* __restrict__ outp) {
  float s1 = 0.f, s2 = 0.f;
  for (int i = threadIdx.x; i < NROWS; i += 256) s1 += rowres[i];
  for (int i = threadIdx.x; i < NPROT; i += 256) s2 += pconbuf[i];
  s1 = blockReduceSum(s1);
  s2 = blockReduceSum(s2);
  if (threadIdx.x == 0) outp[0] = s1 / (float)NROWS + s2 / (float)NPROT;
}

// ---------- host ----------
extern "C" void kernel_launch(void* const* d_in, const int* in_sizes, int n_in,
                              void* d_out, int out_size, void* d_ws, size_t ws_size,
                              hipStream_t stream) {
  (void)in_sizes; (void)n_in; (void)out_size; (void)ws_size;
  const float* features = (const float*)d_in[0];
  const int*   targets  = (const int*)d_in[1];
  const float* beta     = (const float*)d_in[2];
  const float* protos   = (const float*)d_in[3];
  float* outp = (float*)d_out;

  char* basep = (char*)d_ws;
  size_t off = 0;
  auto alloc = [&](size_t bytes) -> void* {
    void* p = basep + off;
    off = (off + bytes + 255) & ~(size_t)255;
    return p;
  };
  _Float16* big  = (_Float16*)alloc((size_t)NROWS * NPROT * 2);   // 40.96 MB
  float* feats   = (float*)alloc((size_t)NROWS * FD * 4);
  short* fhi     = (short*)alloc((size_t)NROWS * FD * 2);
  short* flo     = (short*)alloc((size_t)NROWS * FD * 2);
  short* phi     = (short*)alloc((size_t)NPROT * FD * 2);      // protos, then reused as pn
  short* plo     = (short*)alloc((size_t)NPROT * FD * 2);
  float* part    = (float*)alloc((size_t)128 * PLD * 4);       // GEMM colsum slots (128) >= NSPLIT
  float* Rk      = (float*)alloc(NPROT * 4);
  float* Cn      = (float*)alloc(NROWS * 4);
  int*   idx10   = (int*)alloc(NROWS * TOPK * 4);
  float* wsel    = (float*)alloc((size_t)NROWS * CACHE_SIZE * 4);
  int*   rowlist = (int*)alloc(NROWS * 4);
  int*   classbase = (int*)alloc((NUM_CLASSES + 1) * 4);
  float* uf      = (float*)alloc((size_t)NPROT * FD * 4);
  float* simbuf  = (float*)alloc(NPROT * 4);
  float* scalars = (float*)alloc(64);
  float* rowres  = (float*)alloc(NROWS * 4);
  float* pconbuf = (float*)alloc(NPROT * 4);
  float* pneg    = (float*)alloc((size_t)40 * PLD * 4);
  float* ppos    = (float*)alloc((size_t)40 * PLD * 4);

  k_build_feats<<<512, 256, 0, stream>>>(features, feats, fhi, flo);
  k_split<<<(NPROT * FD / 4 + 255) / 256, 256, 0, stream>>>(protos, NPROT * FD / 4, phi, plo);
  k_counts<<<1, 128, 0, stream>>>(targets, classbase);
  k_rowlist<<<BATCH / 256, 256, 0, stream>>>(targets, classbase, rowlist);

  // GEMM1 (fused colsum pass 1) + rest of sinkhorn1
  k_gemm_mfma<<<dim3(40, 32), 256, 0, stream>>>(fhi, flo, phi, plo, NPROT, big, part);
  k_colsum_fin<<<20, 256, 0, stream>>>(part, 128, Rk);                 // R1
  k_rowsum<<<NROWS, 256, 0, stream>>>(big, Rk, Cn);                    // C1
  k_colsum_part<<<dim3(5, NSPLIT), 256, 0, stream>>>(big, Cn, part);
  k_colsum_fin<<<20, 256, 0, stream>>>(part, NSPLIT, Rk);              // R2
  k_rowsum<<<NROWS, 256, 0, stream>>>(big, Rk, Cn);                    // C2
  k_colsum_part<<<dim3(5, NSPLIT), 256, 0, stream>>>(big, Cn, part);
  k_colsum_fin<<<20, 256, 0, stream>>>(part, NSPLIT, Rk);              // R3

  k_top10<<<16, 256, 0, stream>>>(big, Rk, targets, idx10, wsel);
  k_uf<<<NPROT, 128, 0, stream>>>(feats, wsel, rowlist, classbase, uf);
  k_protoupd<<<NPROT, 128, 0, stream>>>(protos, uf, phi, plo, simbuf); // phi/plo now hold pn
  k_tau<<<1, 256, 0, stream>>>(simbuf, scalars);

  // GEMM2 (fused colsum pass 1) + rest of sinkhorn2
  k_gemm_mfma<<<dim3(40, 32), 256, 0, stream>>>(fhi, flo, phi, plo, NPROT, big, part);
  k_colsum_fin<<<20, 256, 0, stream>>>(part, 128, Rk);                 // R1'
  k_rowsum<<<NROWS, 256, 0, stream>>>(big, Rk, Cn);
  k_colsum_part<<<dim3(5, NSPLIT), 256, 0, stream>>>(big, Cn, part);
  k_colsum_fin<<<20, 256, 0, stream>>>(part, NSPLIT, Rk);              // R2'
  k_rowsum<<<NROWS, 256, 0, stream>>>(big, Rk, Cn);
  k_colsum_part<<<dim3(5, NSPLIT), 256, 0, stream>>>(big, Cn, part);
  k_colsum_fin<<<20, 256, 0, stream>>>(part, NSPLIT, Rk);              // R3'

  k_mle<<<NROWS, 256, 0, stream>>>(big, Rk, targets, idx10, beta, rowres);
  k_pcon_mfma<<<dim3(40, 40), 256, 0, stream>>>(phi, plo, scalars, pneg, ppos);
  k_pcon_fin<<<20, 256, 0, stream>>>(pneg, ppos, pconbuf);
  k_final<<<1, 256, 0, stream>>>(rowres, pconbuf, outp);
}